// Round 2
// baseline (707.265 us; speedup 1.0000x reference)
//
#include <hip/hip_runtime.h>

#define UNITS 16
#define DIMS 272            // 16 + 16*16
#define NGRP 17             // 64-byte groups per row (17 * 4 float4 = 68 float4)

// One THREAD per row. Each lane streams its own row's 17 cache lines
// (4 float4 per line, consumed back-to-back so every fetched line is fully
// used), accumulating against the 272 weights held in LDS (uniform-address
// broadcast reads, conflict-free). No cross-lane reduction at all; stores
// are coalesced (consecutive rows per consecutive lanes).
__global__ __launch_bounds__(256) void linear_pair_gemv(
    const float* __restrict__ in,     // [N, 272] row-major
    const float* __restrict__ kern,   // [16]
    const float* __restrict__ w1p,    // [1]
    const float* __restrict__ w2p,    // [1]
    const float* __restrict__ biasp,  // [1]
    float* __restrict__ out,          // [N]
    int N)
{
    __shared__ __align__(16) float sw[DIMS];

    const int t = threadIdx.x;

    // ---- build the 272 weights in LDS (once per block) ----
    // NOTE: strided loop — DIMS (272) > blockDim (256), a plain `if (t<DIMS)`
    // leaves sw[256..271] uninitialized (round-1 bug, absmax 2.03).
    for (int j = t; j < DIMS; j += 256) {
        float v;
        if (j < UNITS) {
            v = kern[j];
        } else {
            const int p  = j - UNITS;     // 0..255
            const int x1 = p >> 4;        // 0..15
            const int x2 = p & 15;        // 0..15
            const int a1 = x1 >> 2, b1 = x1 & 3;
            const int a2 = x2 >> 2, b2 = x2 & 3;
            v = kern[4 * a1 + a2] * kern[4 * b1 + b2] * w1p[0]
              + kern[4 * a1 + b2] * kern[4 * b1 + a2] * w2p[0];
        }
        sw[j] = v;
    }
    __syncthreads();

    const int row = blockIdx.x * 256 + t;
    if (row >= N) return;                // after the barrier: safe

    const float bias = biasp[0];

    const float4* __restrict__ rp  = (const float4*)(in + (size_t)row * DIMS);
    const float4* __restrict__ swv = (const float4*)sw;

    float4 acc = make_float4(0.f, 0.f, 0.f, 0.f);

    #pragma unroll 2
    for (int g = 0; g < NGRP; ++g) {
        // one full 64B line of this lane's row per iteration
        float4 x0 = rp[4 * g + 0];
        float4 x1 = rp[4 * g + 1];
        float4 x2 = rp[4 * g + 2];
        float4 x3 = rp[4 * g + 3];
        // uniform-address LDS broadcasts (no bank conflicts)
        float4 w0 = swv[4 * g + 0];
        float4 w1 = swv[4 * g + 1];
        float4 w2 = swv[4 * g + 2];
        float4 w3 = swv[4 * g + 3];
        acc.x += x0.x * w0.x + x0.y * w0.y + x0.z * w0.z + x0.w * w0.w;
        acc.y += x1.x * w1.x + x1.y * w1.y + x1.z * w1.z + x1.w * w1.w;
        acc.z += x2.x * w2.x + x2.y * w2.y + x2.z * w2.z + x2.w * w2.w;
        acc.w += x3.x * w3.x + x3.y * w3.y + x3.z * w3.z + x3.w * w3.w;
    }

    out[row] = acc.x + acc.y + acc.z + acc.w + bias;
}

extern "C" void kernel_launch(void* const* d_in, const int* in_sizes, int n_in,
                              void* d_out, int out_size, void* d_ws, size_t ws_size,
                              hipStream_t stream) {
    const float* in    = (const float*)d_in[0];
    const float* kern  = (const float*)d_in[1];
    const float* w1p   = (const float*)d_in[2];
    const float* w2p   = (const float*)d_in[3];
    const float* biasp = (const float*)d_in[4];
    float* out         = (float*)d_out;

    const int N = in_sizes[0] / DIMS;   // 500000

    const int blocks = (N + 255) / 256; // one thread per row
    linear_pair_gemv<<<blocks, 256, 0, stream>>>(in, kern, w1p, w2p, biasp, out, N);
}